// Round 3
// baseline (271.129 us; speedup 1.0000x reference)
//
#include <hip/hip_runtime.h>
#include <stdint.h>

// Guided_Conv: B=16, H=W=384, F=9, P=24, KS=3 -> NB=4096 patches of 24x24x9.
// Raw-reshape algebra: flat patch n = b*256 + i*16 + j (B == nh == nw == 16);
// output patch n occupies flat [n*5184, (n+1)*5184) in C-order (p,q,f).
// ALL tensors fp32 (per the reference's declared dtypes).

// ---------------- Kernel 1: per-patch weight generation (KGL) ----------------
// ws layout per patch (216 floats): w1[kk][12] rows (kk=du*3+dv, f in 0..8
// valid, pads ZEROED), then w2t[o][12] rows (i in 0..8 valid, pads ZEROED).
__global__ __launch_bounds__(256) void kgl_kernel(
    const float* __restrict__ g,
    const float* __restrict__ cw,
    const float* __restrict__ cb,
    const float* __restrict__ dw,
    const float* __restrict__ db,
    float* __restrict__ ws)
{
    __shared__ __align__(16) float sg[5184];   // patch [24][24][9]
    __shared__ float cwf[729];   // conv_w [du][dv][ci][o]
    __shared__ float cbf[9];
    __shared__ float dwf[729];   // dense_w [k][81]
    __shared__ float dbf[81];
    __shared__ float cols[216];  // per-(col,f) sums over rows
    __shared__ float gapm[9];
    __shared__ float cful[81];   // conv out [uv][o], uv=u*3+v
    __shared__ float dld[81];    // dense out [i*9+o]

    const int m = blockIdx.x;
    const int t = threadIdx.x;
    const int b0 = m >> 8, pi = (m >> 4) & 15, pj = m & 15;
    const long rowbase = ((long)(b0 * 384 + pi * 24)) * 3456 + (long)pj * 216;

    // ---- Phase 0: stage patch (float4) + weights (scalar) ----
    for (int task = t; task < 1296; task += 256) {
        int r = task / 54, c = task - r * 54;
        const float4* p = reinterpret_cast<const float4*>(g + rowbase + (long)r * 3456);
        reinterpret_cast<float4*>(sg + r * 216)[c] = p[c];
    }
    for (int idx = t; idx < 729; idx += 256) cwf[idx] = cw[idx];
    for (int idx = t; idx < 729; idx += 256) dwf[idx] = dw[idx];
    if (t < 9) cbf[t] = cb[t];
    if (t >= 32 && t < 113) dbf[t - 32] = db[t - 32];
    // zero the pad slots of this patch's ws region (poison-proof)
    if (t < 216 && (t % 12) >= 9) ws[(long)m * 216 + t] = 0.0f;
    __syncthreads();

    // ---- Phase 1: column sums for GAP ----
    if (t < 216) {
        float s = 0.f;
        #pragma unroll
        for (int r = 0; r < 24; ++r) s += sg[r * 216 + t];
        cols[t] = s;
    }
    __syncthreads();

    // ---- Phase 2: strided 3x3 conv (stride 8; SAME needs no pad here) + GAP ----
    if (t < 81) {
        int o = t % 9, uv = t / 9, v = uv % 3, u = uv / 3;
        float acc = cbf[o];
        #pragma unroll
        for (int du = 0; du < 3; ++du)
        #pragma unroll
        for (int dv = 0; dv < 3; ++dv) {
            const float* gp2 = &sg[(u * 8 + du) * 216 + (v * 8 + dv) * 9];
            const float* wp  = &cwf[(du * 3 + dv) * 81 + o];
            #pragma unroll
            for (int ci = 0; ci < 9; ++ci) acc += gp2[ci] * wp[ci * 9];
        }
        cful[t] = acc;
    }
    if (t >= 216 && t < 225) {
        int f = t - 216; float s = 0.f;
        #pragma unroll
        for (int c = 0; c < 24; ++c) s += cols[c * 9 + f];
        gapm[f] = s * (1.0f / 576.0f);
    }
    __syncthreads();

    // ---- Phase 3: dense + W1 clip/store ----
    if (t < 81) {
        float acc = dbf[t];
        #pragma unroll
        for (int k = 0; k < 9; ++k) acc += gapm[k] * dwf[k * 81 + t];
        dld[t] = acc;
    }
    if (t >= 96 && t < 105) {
        int f = t - 96; float s = 0.f;
        #pragma unroll
        for (int k = 0; k < 9; ++k) { float c = cful[k * 9 + f]; s += c * c; }
        float scale = (s > 1.0f) ? (1.0f / sqrtf(s)) : 1.0f;
        float* wout = ws + (long)m * 216;
        #pragma unroll
        for (int k = 0; k < 9; ++k) wout[k * 12 + f] = cful[k * 9 + f] * scale;
    }
    __syncthreads();

    // ---- Phase 4: W2 clip (over input-channel axis i, per o); store transposed ----
    if (t < 9) {
        float s = 0.f;
        #pragma unroll
        for (int i = 0; i < 9; ++i) { float d = dld[i * 9 + t]; s += d * d; }
        float scale = (s > 1.0f) ? (1.0f / sqrtf(s)) : 1.0f;
        float* wout = ws + (long)m * 216 + 108;
        #pragma unroll
        for (int i = 0; i < 9; ++i) wout[t * 12 + i] = dld[i * 9 + t] * scale;
    }
}

// ---------------- Kernel 2: apply dynamic dwconv + 1x1 mix ----------------
__global__ __launch_bounds__(256) void apply_kernel(
    const float* __restrict__ dep,
    const float* __restrict__ ws,
    float* __restrict__ out)
{
    __shared__ __align__(16) float sd[8112];   // [26][26][12] with halo, zeroed
    __shared__ float sw[216];                  // w1[9][12] + w2t[9][12]
    __shared__ __align__(16) float ob[5184];   // fp32 output staging

    const int m = blockIdx.x;
    const int t = threadIdx.x;
    const int b0 = m >> 8, pi = (m >> 4) & 15, pj = m & 15;
    const long rowbase = ((long)(b0 * 384 + pi * 24)) * 3456 + (long)pj * 216;

    // ---- Phase 0: zero ALL of sd; load per-patch weights ----
    for (int e = t; e < 8112; e += 256) sd[e] = 0.0f;
    if (t < 216) sw[t] = ws[(long)m * 216 + t];
    __syncthreads();

    // ---- Phase 1: fill interior depth values (float4 read, scalar scatter) ----
    for (int task = t; task < 1296; task += 256) {
        int r = task / 54, c4 = task - r * 54;
        const float4* p = reinterpret_cast<const float4*>(dep + rowbase + (long)r * 3456);
        float4 v = p[c4];
        float vv[4] = { v.x, v.y, v.z, v.w };
        int e0 = c4 * 4;
        #pragma unroll
        for (int s = 0; s < 4; ++s) {
            int e = e0 + s;            // 0..215 within the row
            int col = e / 9, f = e - col * 9;
            sd[((r + 1) * 26 + (col + 1)) * 12 + f] = vv[s];
        }
    }
    __syncthreads();

    // ---- Phase 2: 192 threads x 3 consecutive pixels ----
    if (t < 192) {
        const int row = t >> 3;          // 0..23
        const int qb = (t & 7) * 3;      // 0,3,...,21
        float dc[3][9];
        #pragma unroll
        for (int k = 0; k < 3; ++k)
            #pragma unroll
            for (int i = 0; i < 9; ++i) dc[k][i] = 0.f;

        #pragma unroll
        for (int du = 0; du < 3; ++du) {
            float nb[5][9];
            #pragma unroll
            for (int c = 0; c < 5; ++c) {
                const float* sp = &sd[((row + du) * 26 + qb + c) * 12];
                float4 A = *reinterpret_cast<const float4*>(sp);
                float4 B = *reinterpret_cast<const float4*>(sp + 4);
                nb[c][0] = A.x; nb[c][1] = A.y; nb[c][2] = A.z; nb[c][3] = A.w;
                nb[c][4] = B.x; nb[c][5] = B.y; nb[c][6] = B.z; nb[c][7] = B.w;
                nb[c][8] = sp[8];
            }
            #pragma unroll
            for (int dv = 0; dv < 3; ++dv) {
                const float* wv = &sw[(du * 3 + dv) * 12];
                #pragma unroll
                for (int i = 0; i < 9; ++i) {
                    float w = wv[i];
                    dc[0][i] += nb[dv][i]     * w;
                    dc[1][i] += nb[dv + 1][i] * w;
                    dc[2][i] += nb[dv + 2][i] * w;
                }
            }
        }
        float* op = &ob[(row * 24 + qb) * 9];
        #pragma unroll
        for (int o = 0; o < 9; ++o) {
            const float* wv = &sw[108 + o * 12];
            float a0 = 0.f, a1 = 0.f, a2 = 0.f;
            #pragma unroll
            for (int i = 0; i < 9; ++i) {
                float w = wv[i];
                a0 += dc[0][i] * w; a1 += dc[1][i] * w; a2 += dc[2][i] * w;
            }
            op[o]      = a0;
            op[9 + o]  = a1;
            op[18 + o] = a2;
        }
    }
    __syncthreads();

    // ---- Phase 3: vectorized copy-out (1296 x float4 per patch) ----
    {
        const float4* src = reinterpret_cast<const float4*>(ob);
        float4* dst = reinterpret_cast<float4*>(out) + (long)m * 1296;
        for (int k = t; k < 1296; k += 256) dst[k] = src[k];
    }
}

extern "C" void kernel_launch(void* const* d_in, const int* in_sizes, int n_in,
                              void* d_out, int out_size, void* d_ws, size_t ws_size,
                              hipStream_t stream) {
    const float* g  = (const float*)d_in[0];
    const float* dp = (const float*)d_in[1];
    const float* cw = (const float*)d_in[2];
    const float* cb = (const float*)d_in[3];
    const float* dw = (const float*)d_in[4];
    const float* db = (const float*)d_in[5];
    float* ws = (float*)d_ws;
    float* out = (float*)d_out;

    kgl_kernel<<<dim3(4096), dim3(256), 0, stream>>>(g, cw, cb, dw, db, ws);
    apply_kernel<<<dim3(4096), dim3(256), 0, stream>>>(dp, ws, out);
}

// Round 4
// 254.785 us; speedup vs baseline: 1.0642x; 1.0642x over previous
//
#include <hip/hip_runtime.h>
#include <stdint.h>

// Guided_Conv: B=16, H=W=384, F=9, P=24, KS=3 -> NB=4096 patches of 24x24x9.
// Raw-reshape algebra: flat patch n = b*256 + i*16 + j (B == nh == nw == 16);
// output patch n occupies flat [n*5184, (n+1)*5184) in C-order (p,q,f).
// ALL tensors fp32. ws layout per patch (216 floats): w1[kk][12] (kk=du*3+dv,
// f 0..8 valid) then w2t[o][12] (i 0..8 valid); pads zeroed by kgl.

// ---------------- Kernel 1: per-patch weight generation (KGL) ----------------
__global__ __launch_bounds__(256) void kgl_kernel(
    const float* __restrict__ g,
    const float* __restrict__ cw,
    const float* __restrict__ cb,
    const float* __restrict__ dw,
    const float* __restrict__ db,
    float* __restrict__ ws)
{
    __shared__ __align__(16) float sg[5184];   // patch [24][24][9]
    __shared__ float cwf[729];   // conv_w [du][dv][ci][o]
    __shared__ float cbf[9];
    __shared__ float dwf[729];   // dense_w [k][81]
    __shared__ float dbf[81];
    __shared__ float cols[216];  // per-(col,f) sums over rows
    __shared__ float gapm[9];
    __shared__ float cful[81];   // conv out [uv][o], uv=u*3+v
    __shared__ float dld[81];    // dense out [i*9+o]

    const int m = blockIdx.x;
    const int t = threadIdx.x;
    const int b0 = m >> 8, pi = (m >> 4) & 15, pj = m & 15;
    const long rowbase = ((long)(b0 * 384 + pi * 24)) * 3456 + (long)pj * 216;

    // ---- Phase 0: stage patch (float4) + weights ----
    for (int task = t; task < 1296; task += 256) {
        int r = task / 54, c = task - r * 54;
        const float4* p = reinterpret_cast<const float4*>(g + rowbase + (long)r * 3456);
        reinterpret_cast<float4*>(sg + r * 216)[c] = p[c];
    }
    for (int idx = t; idx < 729; idx += 256) cwf[idx] = cw[idx];
    for (int idx = t; idx < 729; idx += 256) dwf[idx] = dw[idx];
    if (t < 9) cbf[t] = cb[t];
    if (t >= 32 && t < 113) dbf[t - 32] = db[t - 32];
    if (t < 216 && (t % 12) >= 9) ws[(long)m * 216 + t] = 0.0f; // zero pad slots
    __syncthreads();

    // ---- Phase 1: column sums for GAP ----
    if (t < 216) {
        float s = 0.f;
        #pragma unroll
        for (int r = 0; r < 24; ++r) s += sg[r * 216 + t];
        cols[t] = s;
    }
    __syncthreads();

    // ---- Phase 2: strided 3x3 conv (stride 8; SAME -> in-bounds here) + GAP ----
    if (t < 81) {
        int o = t % 9, uv = t / 9, v = uv % 3, u = uv / 3;
        float acc = cbf[o];
        #pragma unroll
        for (int du = 0; du < 3; ++du)
        #pragma unroll
        for (int dv = 0; dv < 3; ++dv) {
            const float* gp2 = &sg[(u * 8 + du) * 216 + (v * 8 + dv) * 9];
            const float* wp  = &cwf[(du * 3 + dv) * 81 + o];
            #pragma unroll
            for (int ci = 0; ci < 9; ++ci) acc += gp2[ci] * wp[ci * 9];
        }
        cful[t] = acc;
    }
    if (t >= 216 && t < 225) {
        int f = t - 216; float s = 0.f;
        #pragma unroll
        for (int c = 0; c < 24; ++c) s += cols[c * 9 + f];
        gapm[f] = s * (1.0f / 576.0f);
    }
    __syncthreads();

    // ---- Phase 3: dense + W1 clip/store ----
    if (t < 81) {
        float acc = dbf[t];
        #pragma unroll
        for (int k = 0; k < 9; ++k) acc += gapm[k] * dwf[k * 81 + t];
        dld[t] = acc;
    }
    if (t >= 96 && t < 105) {
        int f = t - 96; float s = 0.f;
        #pragma unroll
        for (int k = 0; k < 9; ++k) { float c = cful[k * 9 + f]; s += c * c; }
        float scale = (s > 1.0f) ? (1.0f / sqrtf(s)) : 1.0f;
        float* wout = ws + (long)m * 216;
        #pragma unroll
        for (int k = 0; k < 9; ++k) wout[k * 12 + f] = cful[k * 9 + f] * scale;
    }
    __syncthreads();

    // ---- Phase 4: W2 clip (over input-channel axis i, per o); store transposed ----
    if (t < 9) {
        float s = 0.f;
        #pragma unroll
        for (int i = 0; i < 9; ++i) { float d = dld[i * 9 + t]; s += d * d; }
        float scale = (s > 1.0f) ? (1.0f / sqrtf(s)) : 1.0f;
        float* wout = ws + (long)m * 216 + 108;
        #pragma unroll
        for (int i = 0; i < 9; ++i) wout[t * 12 + i] = dld[i * 9 + t] * scale;
    }
}

// ---------------- Kernel 2: apply dynamic dwconv + 1x1 mix ----------------
// 576 threads = 1 pixel/thread. sd [26][26][12] halo layout; only the halo
// ring is zeroed (interior f-pads are never read). Single barrier. Direct
// coalesced global stores (9 contiguous floats/thread).
__global__ __launch_bounds__(576, 7) void apply_kernel(
    const float* __restrict__ dep,
    const float* __restrict__ ws,
    float* __restrict__ out)
{
    __shared__ __align__(16) float sd[8112];   // [26][26][12] with halo
    __shared__ float sw[216];                  // w1[9][12] + w2t[9][12]

    const int m = blockIdx.x;
    const int t = threadIdx.x;
    const int b0 = m >> 8, pi = (m >> 4) & 15, pj = m & 15;
    const long rowbase = ((long)(b0 * 384 + pi * 24)) * 3456 + (long)pj * 216;

    // ---- Phase 0 (concurrent, disjoint): halo zero + weights + interior fill ----
    if (t < 100) {                 // halo ring: 100 pixels x 12 floats
        int r, c;
        if (t < 26)      { r = 0;       c = t;      }
        else if (t < 52) { r = 25;      c = t - 26; }
        else if (t < 76) { r = t - 51;  c = 0;      }
        else             { r = t - 75;  c = 25;     }
        float4 z = make_float4(0.f, 0.f, 0.f, 0.f);
        float4* p = reinterpret_cast<float4*>(&sd[(r * 26 + c) * 12]);
        p[0] = z; p[1] = z; p[2] = z;
    }
    if (t >= 128 && t < 344) sw[t - 128] = ws[(long)m * 216 + (t - 128)];
    for (int task = t; task < 1296; task += 576) {   // interior rows 1..24, cols 1..24
        int r = task / 54, c4 = task - r * 54;
        const float4* p = reinterpret_cast<const float4*>(dep + rowbase + (long)r * 3456);
        float4 v = p[c4];
        float vv[4] = { v.x, v.y, v.z, v.w };
        int e0 = c4 * 4;
        #pragma unroll
        for (int s = 0; s < 4; ++s) {
            int e = e0 + s;                 // 0..215 within the row
            int col = e / 9, f = e - col * 9;
            sd[((r + 1) * 26 + (col + 1)) * 12 + f] = vv[s];
        }
    }
    __syncthreads();

    // ---- Phase 1: compute 1 pixel/thread, store direct ----
    {
        const int row = t / 24;            // 0..23
        const int col = t - row * 24;      // 0..23
        float dc[9];
        #pragma unroll
        for (int i = 0; i < 9; ++i) dc[i] = 0.f;

        #pragma unroll
        for (int du = 0; du < 3; ++du)
        #pragma unroll
        for (int dv = 0; dv < 3; ++dv) {
            const float* sp = &sd[((row + du) * 26 + (col + dv)) * 12];
            const float* wv = &sw[(du * 3 + dv) * 12];
            float4 A = *reinterpret_cast<const float4*>(sp);
            float4 B = *reinterpret_cast<const float4*>(sp + 4);
            float a8 = sp[8];
            dc[0] += A.x * wv[0]; dc[1] += A.y * wv[1]; dc[2] += A.z * wv[2];
            dc[3] += A.w * wv[3]; dc[4] += B.x * wv[4]; dc[5] += B.y * wv[5];
            dc[6] += B.z * wv[6]; dc[7] += B.w * wv[7]; dc[8] += a8  * wv[8];
        }

        float* op = out + (long)m * 5184 + t * 9;
        #pragma unroll
        for (int o = 0; o < 9; ++o) {
            const float* wv = &sw[108 + o * 12];
            float a = 0.f;
            #pragma unroll
            for (int i = 0; i < 9; ++i) a += dc[i] * wv[i];
            op[o] = a;
        }
    }
}

extern "C" void kernel_launch(void* const* d_in, const int* in_sizes, int n_in,
                              void* d_out, int out_size, void* d_ws, size_t ws_size,
                              hipStream_t stream) {
    const float* g  = (const float*)d_in[0];
    const float* dp = (const float*)d_in[1];
    const float* cw = (const float*)d_in[2];
    const float* cb = (const float*)d_in[3];
    const float* dw = (const float*)d_in[4];
    const float* db = (const float*)d_in[5];
    float* ws = (float*)d_ws;
    float* out = (float*)d_out;

    kgl_kernel<<<dim3(4096), dim3(256), 0, stream>>>(g, cw, cb, dw, db, ws);
    apply_kernel<<<dim3(4096), dim3(576), 0, stream>>>(dp, ws, out);
}